// Round 5
// baseline (77.263 us; speedup 1.0000x reference)
//
#include <hip/hip_runtime.h>

// BipartPool fused: GATv2 bipartite pooling, fully-regular structure.
// lrelu(z) = 0.6z + 0.4|z| -> logit = dot(xl,att6) + xr_att6[r,h] + sum_c |xl+xr|*att4
// No-max softmax (logits ~N(0,1), f32 exp safe): alpha = ex/den, den divided out at the
// end; PV runs on unnormalized ex, den comes free as a ones-column MFMA.
// K1 (only big kernel): per 64-node tile: MFMA x@W_l -> xlT(LDS) -> logit pass (xv/a4 in
// VGPRs, xr rows streamed as wave-uniform s_loads) -> ex(LDS) -> MFMA ex^T@xl -> private
// per-tile partial slots; last block of each graph (atomic counter) reduces 16 tiles,
// divides by den, head-means, adds bias, writes out + batchcent.

typedef __attribute__((ext_vector_type(8))) short short8;
typedef __attribute__((ext_vector_type(4))) float f32x4;

#define NPG 1024
#define NT 512

static __device__ __forceinline__ unsigned short f2bf(float f) {
    unsigned int u = __float_as_uint(f);
    u += 0x7fffu + ((u >> 16) & 1u);        // RNE (data is normal, no NaN handling)
    return (unsigned short)(u >> 16);
}
static __device__ __forceinline__ float bf2f(unsigned short u) {
    return __uint_as_float(((unsigned int)u) << 16);
}

// ---------------- K0: tables: xr2[r][hc], xr_att6[r*4+h], att6/att4, Wt bf16; cnt=0 ------
__global__ __launch_bounds__(256) void k0_prep(const float* __restrict__ xcb,
                                               const float* __restrict__ W_l,
                                               const float* __restrict__ W_r,
                                               const float* __restrict__ b_r,
                                               const float* __restrict__ att,
                                               float* __restrict__ xr2,
                                               float* __restrict__ xr_att6,
                                               float* __restrict__ att6,
                                               float* __restrict__ att4,
                                               unsigned short* __restrict__ wt,
                                               int* __restrict__ cnt) {
    int b = blockIdx.x, t = threadIdx.x;
    if (b < 16) {
        int r = b, hc = t;                  // one wave per head; W_r coalesced over hc
        float v = b_r[hc];
#pragma unroll
        for (int k = 0; k < 64; ++k)
            v = fmaf(xcb[r * 64 + k], W_r[k * 256 + hc], v);
        xr2[r * 256 + hc] = v;              // row-major by r: s_load-streamable in k1
        float p = 0.6f * att[hc] * v;
        p += __shfl_xor(p, 1);  p += __shfl_xor(p, 2);
        p += __shfl_xor(p, 4);  p += __shfl_xor(p, 8);
        p += __shfl_xor(p, 16); p += __shfl_xor(p, 32);
        if ((t & 63) == 0) xr_att6[r * 4 + (t >> 6)] = p;
    } else {
        att6[t] = 0.6f * att[t];
        att4[t] = 0.4f * att[t];
        // Wt[c][k] = bf16(W_l[k][c])  (k-contiguous for MFMA B-frags)
        unsigned short tmp[64] __attribute__((aligned(16)));
#pragma unroll
        for (int k = 0; k < 64; ++k) tmp[k] = f2bf(W_l[k * 256 + t]);
#pragma unroll
        for (int q = 0; q < 8; ++q)
            *(short8*)(wt + t * 64 + q * 8) = *(const short8*)(tmp + q * 8);
        if (t < 32) cnt[t] = 0;             // per-graph finalize counters (every call)
    }
}

// ---------------- K1: fused xl -> logits -> ex -> PV partials -> last-block finalize -----
__global__ __launch_bounds__(256, 2) void k1_fused(const float* __restrict__ x,
                                                   const unsigned short* __restrict__ wt,
                                                   const float* __restrict__ b_l,
                                                   const float* __restrict__ att6,
                                                   const float* __restrict__ att4,
                                                   const float* __restrict__ xr2,
                                                   const float* __restrict__ xr_att6,
                                                   const float* __restrict__ bias,
                                                   float* __restrict__ ws_pv,
                                                   float* __restrict__ ws_denp,
                                                   int* __restrict__ cnt,
                                                   float* __restrict__ out) {
    __shared__ __align__(16) unsigned char smraw[(256 + 64) * 72 * 2];
    __shared__ int s_flag;
    unsigned short (*As)[72]  = (unsigned short (*)[72])smraw;             // 64x72 (aliases xlT)
    unsigned short (*xlT)[72] = (unsigned short (*)[72])smraw;             // [h*64+c][n]
    unsigned short (*exT)[72] = (unsigned short (*)[72])(smraw + 256 * 72 * 2); // [h*16+r][n]

    const int t = threadIdx.x;
    const int blk = blockIdx.x;              // 512 = g(32) x tile(16)
    const int g = blk >> 4;
    const int n0 = blk * 64;

    // ---- phase A: stage x[64n][64k] f32 -> bf16 As ----
    {
        int n = t >> 2, q = (t & 3) * 16;
        const float* p = x + (size_t)(n0 + n) * 64 + q;
        float4 v0 = *(const float4*)p;
        float4 v1 = *(const float4*)(p + 4);
        float4 v2 = *(const float4*)(p + 8);
        float4 v3 = *(const float4*)(p + 12);
        unsigned short h16[16] __attribute__((aligned(16)));
        h16[0]=f2bf(v0.x); h16[1]=f2bf(v0.y); h16[2]=f2bf(v0.z); h16[3]=f2bf(v0.w);
        h16[4]=f2bf(v1.x); h16[5]=f2bf(v1.y); h16[6]=f2bf(v1.z); h16[7]=f2bf(v1.w);
        h16[8]=f2bf(v2.x); h16[9]=f2bf(v2.y); h16[10]=f2bf(v2.z); h16[11]=f2bf(v2.w);
        h16[12]=f2bf(v3.x); h16[13]=f2bf(v3.y); h16[14]=f2bf(v3.z); h16[15]=f2bf(v3.w);
        *(short8*)(&As[n][q])     = *(const short8*)h16;
        *(short8*)(&As[n][q + 8]) = *(const short8*)(h16 + 8);
    }
    __syncthreads();

    const int l = t & 63;
    const int h = __builtin_amdgcn_readfirstlane(t >> 6);
    const int lm = l & 15, lk = (l >> 4) * 8;

    // ---- phase B: MFMA C[64n][64c] = x @ W_l(head h) ----
    short8 af[4][2], bfr[4][2];
#pragma unroll
    for (int mt = 0; mt < 4; ++mt)
#pragma unroll
        for (int ks = 0; ks < 2; ++ks)
            af[mt][ks] = *(const short8*)(&As[mt * 16 + lm][ks * 32 + lk]);
#pragma unroll
    for (int nt = 0; nt < 4; ++nt)
#pragma unroll
        for (int ks = 0; ks < 2; ++ks)
            bfr[nt][ks] = *(const short8*)(wt + (size_t)(h * 64 + nt * 16 + lm) * 64 + ks * 32 + lk);

    f32x4 acc[4][4];
#pragma unroll
    for (int mt = 0; mt < 4; ++mt)
#pragma unroll
        for (int nt = 0; nt < 4; ++nt) { f32x4 z = {0.f,0.f,0.f,0.f}; acc[mt][nt] = z; }
#pragma unroll
    for (int mt = 0; mt < 4; ++mt)
#pragma unroll
        for (int nt = 0; nt < 4; ++nt)
#pragma unroll
            for (int ks = 0; ks < 2; ++ks)
                acc[mt][nt] = __builtin_amdgcn_mfma_f32_16x16x32_bf16(
                    af[mt][ks], bfr[nt][ks], acc[mt][nt], 0, 0, 0);

    __syncthreads();   // all waves done reading As; xlT may overwrite it

    // ---- phase C: acc(+b_l) -> xlT[h*64+c][n] bf16 ----
    // C layout: col = lane&15 (+nt*16), row(n) = (lane>>4)*4 + j (+mt*16)   [m89-verified]
#pragma unroll
    for (int nt = 0; nt < 4; ++nt) {
        float bl = b_l[h * 64 + nt * 16 + lm];
#pragma unroll
        for (int mt = 0; mt < 4; ++mt) {
            unsigned int d0 = (unsigned int)f2bf(acc[mt][nt][0] + bl) |
                              ((unsigned int)f2bf(acc[mt][nt][1] + bl) << 16);
            unsigned int d1 = (unsigned int)f2bf(acc[mt][nt][2] + bl) |
                              ((unsigned int)f2bf(acc[mt][nt][3] + bl) << 16);
            *(uint2*)(&xlT[h * 64 + nt * 16 + lm][mt * 16 + (l >> 4) * 4]) = make_uint2(d0, d1);
        }
    }

    // ---- phase D: logits. xv & a4 in VGPRs; xr rows = wave-uniform s_load streams ----
    float xv[64], a4v[64];
#pragma unroll
    for (int c = 0; c < 64; ++c) xv[c] = bf2f(xlT[h * 64 + c][l]);
#pragma unroll
    for (int c = 0; c < 64; ++c) a4v[c] = att4[h * 64 + c];
    float base = 0.f;
#pragma unroll
    for (int c = 0; c < 64; ++c) base = fmaf(xv[c], att6[h * 64 + c], base);

    const float* xr2h = xr2 + h * 64;
#pragma unroll
    for (int r = 0; r < 16; ++r) {           // fully unrolled: no dynamic-index scratch
        const float* xp = xr2h + r * 256;
        float a0 = 0.f, a1 = 0.f, a2 = 0.f, a3 = 0.f;
#pragma unroll
        for (int c = 0; c < 64; c += 4) {
            a0 = fmaf(fabsf(xv[c + 0] + xp[c + 0]), a4v[c + 0], a0);
            a1 = fmaf(fabsf(xv[c + 1] + xp[c + 1]), a4v[c + 1], a1);
            a2 = fmaf(fabsf(xv[c + 2] + xp[c + 2]), a4v[c + 2], a2);
            a3 = fmaf(fabsf(xv[c + 3] + xp[c + 3]), a4v[c + 3], a3);
        }
        float ex = __expf(base + ((a0 + a1) + (a2 + a3)) + xr_att6[r * 4 + h]);
        exT[h * 16 + r][l] = f2bf(ex);       // no-max softmax (logits ~N(0,1))
    }

    // ---- phase E: PV MFMA: pacc[16r][64c] = ex^T @ xl ; ones-col B gives den ----
    short8 ap[2];
#pragma unroll
    for (int ks = 0; ks < 2; ++ks)
        ap[ks] = *(const short8*)(&exT[h * 16 + lm][ks * 32 + lk]);
    short o = (lm == 0) ? (short)0x3F80 : (short)0;   // bf16 1.0 in column 0
    short8 onesf = {o, o, o, o, o, o, o, o};

    f32x4 pacc[4], dacc;
    { f32x4 z = {0.f,0.f,0.f,0.f}; pacc[0]=z; pacc[1]=z; pacc[2]=z; pacc[3]=z; dacc=z; }
#pragma unroll
    for (int ks = 0; ks < 2; ++ks) {
#pragma unroll
        for (int nt = 0; nt < 4; ++nt) {
            short8 bp = *(const short8*)(&xlT[h * 64 + nt * 16 + lm][ks * 32 + lk]);
            pacc[nt] = __builtin_amdgcn_mfma_f32_16x16x32_bf16(ap[ks], bp, pacc[nt], 0, 0, 0);
        }
        dacc = __builtin_amdgcn_mfma_f32_16x16x32_bf16(ap[ks], onesf, dacc, 0, 0, 0);
    }

    // ---- store per-tile partials: pv[blk][h][16r][64c], denp[blk][h][16r] ----
    float* pvb = ws_pv + ((size_t)blk * 4 + h) * 1024;
#pragma unroll
    for (int nt = 0; nt < 4; ++nt)
#pragma unroll
        for (int j = 0; j < 4; ++j)
            pvb[((l >> 4) * 4 + j) * 64 + nt * 16 + lm] = pacc[nt][j];
    if (lm == 0) {
#pragma unroll
        for (int j = 0; j < 4; ++j)
            ws_denp[((size_t)blk * 4 + h) * 16 + (l >> 4) * 4 + j] = dacc[j];
    }

    // ---- last block of each graph finalizes (deterministic: atomics only elect) ----
    __syncthreads();                          // drains vmcnt: all block stores issued
    if (t == 0) {
        __threadfence();                      // release partials device-wide
        s_flag = (atomicAdd(&cnt[g], 1) == 15);
    }
    __syncthreads();
    if (!s_flag) return;
    __threadfence();                          // acquire other blocks' partials

    int c = t & 63, r0 = t >> 6;
    float vout[4];
#pragma unroll
    for (int j = 0; j < 4; ++j) {
        int r = r0 * 4 + j;
        float s = 0.f;
#pragma unroll
        for (int hh = 0; hh < 4; ++hh) {
            float num = 0.f, den = 0.f;
#pragma unroll
            for (int tl = 0; tl < 16; ++tl) {
                num += ws_pv[(((size_t)(g * 16 + tl)) * 4 + hh) * 1024 + r * 64 + c];
                den += ws_denp[((size_t)(g * 16 + tl) * 4 + hh) * 16 + r];
            }
            s += num / den;
        }
        vout[j] = fmaf(0.25f, s, bias[c]);
    }
#pragma unroll
    for (int j = 0; j < 4; ++j)
        out[((size_t)g * 16 + r0 * 4 + j) * 64 + c] = vout[j];
    if (t < 16) out[NT * 64 + g * 16 + t] = (float)g;   // batchcent
}

extern "C" void kernel_launch(void* const* d_in, const int* in_sizes, int n_in,
                              void* d_out, int out_size, void* d_ws, size_t ws_size,
                              hipStream_t stream) {
    const float* x    = (const float*)d_in[0];
    const float* xcb  = (const float*)d_in[3];
    const float* W_l  = (const float*)d_in[4];
    const float* b_l  = (const float*)d_in[5];
    const float* W_r  = (const float*)d_in[6];
    const float* b_r  = (const float*)d_in[7];
    const float* att  = (const float*)d_in[8];
    const float* bias = (const float*)d_in[9];
    float* out = (float*)d_out;

    // workspace layout (~8.3 MB)
    float* ws_pv   = (float*)d_ws;                   // 512 blk x 4 h x 16 r x 64 c = 8 MB
    float* ws_denp = ws_pv + 2097152;                // 512 x 4 x 16
    float* xr2     = ws_denp + 32768;                // [16r][256hc]
    float* xr_att6 = xr2 + 4096;                     // 64
    float* att6    = xr_att6 + 64;                   // 256
    float* att4    = att6 + 256;                     // 256
    unsigned short* wt = (unsigned short*)(att4 + 256);   // 256x64 bf16
    int* cnt = (int*)(wt + 16384);                   // 32 per-graph counters

    k0_prep<<<17, 256, 0, stream>>>(xcb, W_l, W_r, b_r, att, xr2, xr_att6, att6, att4, wt, cnt);
    k1_fused<<<512, 256, 0, stream>>>(x, wt, b_l, att6, att4, xr2, xr_att6, bias,
                                      ws_pv, ws_denp, cnt, out);
}

// Round 6
// 71.498 us; speedup vs baseline: 1.0806x; 1.0806x over previous
//
#include <hip/hip_runtime.h>

// BipartPool fused: GATv2 bipartite pooling, fully-regular structure.
// lrelu(z) = 0.6z + 0.4|z| -> logit = dot(xl,att6) + xr_att6[r,h] + sum_c |xl+xr|*att4
// No-max softmax (logits ~N(0,1), f32 exp safe): alpha = ex/den, den divided out at the
// end; PV runs on unnormalized ex, den comes free as a ones-column MFMA.
// K1: per 64-node tile: MFMA x@W_l -> xlT(LDS) -> logit pass (R4-proven streaming form:
// lacc[16], xr rows via wave-uniform loads -- NO big per-thread arrays, no spills) ->
// ex(LDS) -> MFMA ex^T@xl -> bf16 per-tile partial slots; last block per graph (atomic
// counter election; values deterministic) reduces 16 tiles, divides by den, head-means,
// adds bias, writes out. batchcent is input-independent -> written by k0.

typedef __attribute__((ext_vector_type(8))) short short8;
typedef __attribute__((ext_vector_type(4))) float f32x4;

#define NPG 1024
#define NT 512

static __device__ __forceinline__ unsigned short f2bf(float f) {
    unsigned int u = __float_as_uint(f);
    u += 0x7fffu + ((u >> 16) & 1u);        // RNE (data is normal, no NaN handling)
    return (unsigned short)(u >> 16);
}
static __device__ __forceinline__ float bf2f(unsigned short u) {
    return __uint_as_float(((unsigned int)u) << 16);
}

// ---------------- K0: tables xrT[hc][16r], xr_att6, att6/att4, Wt bf16; cnt=0; batchcent --
__global__ __launch_bounds__(256) void k0_prep(const float* __restrict__ xcb,
                                               const float* __restrict__ W_l,
                                               const float* __restrict__ W_r,
                                               const float* __restrict__ b_r,
                                               const float* __restrict__ att,
                                               float* __restrict__ xrT,
                                               float* __restrict__ xr_att6,
                                               float* __restrict__ att6,
                                               float* __restrict__ att4,
                                               unsigned short* __restrict__ wt,
                                               int* __restrict__ cnt,
                                               float* __restrict__ out) {
    int b = blockIdx.x, t = threadIdx.x;
    if (b < 16) {
        int r = b, hc = t;                  // one wave per head; W_r coalesced over hc
        float v = b_r[hc];
#pragma unroll
        for (int k = 0; k < 64; ++k)
            v = fmaf(xcb[r * 64 + k], W_r[k * 256 + hc], v);
        xrT[hc * 16 + r] = v;               // [hc][16r]: k1 streams 16-r rows per c
        float p = 0.6f * att[hc] * v;
        p += __shfl_xor(p, 1);  p += __shfl_xor(p, 2);
        p += __shfl_xor(p, 4);  p += __shfl_xor(p, 8);
        p += __shfl_xor(p, 16); p += __shfl_xor(p, 32);
        if ((t & 63) == 0) xr_att6[r * 4 + (t >> 6)] = p;
    } else {
        att6[t] = 0.6f * att[t];
        att4[t] = 0.4f * att[t];
        // Wt[c][k] = bf16(W_l[k][c])  (k-contiguous for MFMA B-frags)
        unsigned short tmp[64] __attribute__((aligned(16)));
#pragma unroll
        for (int k = 0; k < 64; ++k) tmp[k] = f2bf(W_l[k * 256 + t]);
#pragma unroll
        for (int q = 0; q < 8; ++q)
            *(short8*)(wt + t * 64 + q * 8) = *(const short8*)(tmp + q * 8);
        if (t < 32) cnt[t] = 0;             // per-graph finalize counters (every call)
        // batchcent: input-independent
        out[NT * 64 + t]       = (float)(t >> 4);
        out[NT * 64 + 256 + t] = (float)((256 + t) >> 4);
    }
}

// ---------------- K1: fused xl -> logits -> ex -> PV partials -> last-block finalize -----
__global__ __launch_bounds__(256, 2) void k1_fused(const float* __restrict__ x,
                                                   const unsigned short* __restrict__ wt,
                                                   const float* __restrict__ b_l,
                                                   const float* __restrict__ att6,
                                                   const float* __restrict__ att4,
                                                   const float* __restrict__ xrT,
                                                   const float* __restrict__ xr_att6,
                                                   const float* __restrict__ bias,
                                                   unsigned short* __restrict__ ws_pvh,
                                                   float* __restrict__ ws_denp,
                                                   int* __restrict__ cnt,
                                                   float* __restrict__ out) {
    __shared__ __align__(16) unsigned char smraw[(256 + 64) * 72 * 2];
    __shared__ int s_flag;
    unsigned short (*As)[72]  = (unsigned short (*)[72])smraw;             // 64x72 (aliases xlT)
    unsigned short (*xlT)[72] = (unsigned short (*)[72])smraw;             // [h*64+c][n]
    unsigned short (*exT)[72] = (unsigned short (*)[72])(smraw + 256 * 72 * 2); // [h*16+r][n]

    const int t = threadIdx.x;
    const int blk = blockIdx.x;              // 512 = g(32) x tile(16)
    const int g = blk >> 4;
    const int n0 = blk * 64;

    // ---- phase A: stage x[64n][64k] f32 -> bf16 As ----
    {
        int n = t >> 2, q = (t & 3) * 16;
        const float* p = x + (size_t)(n0 + n) * 64 + q;
        float4 v0 = *(const float4*)p;
        float4 v1 = *(const float4*)(p + 4);
        float4 v2 = *(const float4*)(p + 8);
        float4 v3 = *(const float4*)(p + 12);
        unsigned short h16[16] __attribute__((aligned(16)));
        h16[0]=f2bf(v0.x); h16[1]=f2bf(v0.y); h16[2]=f2bf(v0.z); h16[3]=f2bf(v0.w);
        h16[4]=f2bf(v1.x); h16[5]=f2bf(v1.y); h16[6]=f2bf(v1.z); h16[7]=f2bf(v1.w);
        h16[8]=f2bf(v2.x); h16[9]=f2bf(v2.y); h16[10]=f2bf(v2.z); h16[11]=f2bf(v2.w);
        h16[12]=f2bf(v3.x); h16[13]=f2bf(v3.y); h16[14]=f2bf(v3.z); h16[15]=f2bf(v3.w);
        *(short8*)(&As[n][q])     = *(const short8*)h16;
        *(short8*)(&As[n][q + 8]) = *(const short8*)(h16 + 8);
    }
    __syncthreads();

    const int l = t & 63;
    const int h = __builtin_amdgcn_readfirstlane(t >> 6);
    const int lm = l & 15, lk = (l >> 4) * 8;

    // ---- phase B: MFMA C[64n][64c] = x @ W_l(head h) ----
    short8 af[4][2], bfr[4][2];
#pragma unroll
    for (int mt = 0; mt < 4; ++mt)
#pragma unroll
        for (int ks = 0; ks < 2; ++ks)
            af[mt][ks] = *(const short8*)(&As[mt * 16 + lm][ks * 32 + lk]);
#pragma unroll
    for (int nt = 0; nt < 4; ++nt)
#pragma unroll
        for (int ks = 0; ks < 2; ++ks)
            bfr[nt][ks] = *(const short8*)(wt + (size_t)(h * 64 + nt * 16 + lm) * 64 + ks * 32 + lk);

    f32x4 acc[4][4];
#pragma unroll
    for (int mt = 0; mt < 4; ++mt)
#pragma unroll
        for (int nt = 0; nt < 4; ++nt) { f32x4 z = {0.f,0.f,0.f,0.f}; acc[mt][nt] = z; }
#pragma unroll
    for (int mt = 0; mt < 4; ++mt)
#pragma unroll
        for (int nt = 0; nt < 4; ++nt)
#pragma unroll
            for (int ks = 0; ks < 2; ++ks)
                acc[mt][nt] = __builtin_amdgcn_mfma_f32_16x16x32_bf16(
                    af[mt][ks], bfr[nt][ks], acc[mt][nt], 0, 0, 0);

    __syncthreads();   // all waves done reading As; xlT may overwrite it

    // ---- phase C: acc(+b_l) -> xlT[h*64+c][n] bf16 ----
    // C layout: col = lane&15 (+nt*16), row(n) = (lane>>4)*4 + j (+mt*16)   [m89-verified]
#pragma unroll
    for (int nt = 0; nt < 4; ++nt) {
        float bl = b_l[h * 64 + nt * 16 + lm];
#pragma unroll
        for (int mt = 0; mt < 4; ++mt) {
            unsigned int d0 = (unsigned int)f2bf(acc[mt][nt][0] + bl) |
                              ((unsigned int)f2bf(acc[mt][nt][1] + bl) << 16);
            unsigned int d1 = (unsigned int)f2bf(acc[mt][nt][2] + bl) |
                              ((unsigned int)f2bf(acc[mt][nt][3] + bl) << 16);
            *(uint2*)(&xlT[h * 64 + nt * 16 + lm][mt * 16 + (l >> 4) * 4]) = make_uint2(d0, d1);
        }
    }

    // ---- phase D (R4-proven): stream c; lacc[16]; xr/att wave-uniform loads ----
    float base = 0.f;
    float lacc[16];
#pragma unroll
    for (int r = 0; r < 16; ++r) lacc[r] = 0.f;
#pragma unroll 8
    for (int c = 0; c < 64; ++c) {
        float xv = bf2f(xlT[h * 64 + c][l]);
        base = fmaf(xv, att6[h * 64 + c], base);
        float a4 = att4[h * 64 + c];
        const float* xp = xrT + (size_t)(h * 64 + c) * 16;
#pragma unroll
        for (int r = 0; r < 16; ++r)
            lacc[r] = fmaf(fabsf(xv + xp[r]), a4, lacc[r]);   // abs = free VOP3 modifier
    }
#pragma unroll
    for (int r = 0; r < 16; ++r) {
        float ex = __expf(base + lacc[r] + xr_att6[r * 4 + h]);   // no-max softmax
        exT[h * 16 + r][l] = f2bf(ex);
    }

    // ---- phase E: PV MFMA: pacc[16r][64c] = ex^T @ xl ; ones-col B gives den ----
    short8 ap[2];
#pragma unroll
    for (int ks = 0; ks < 2; ++ks)
        ap[ks] = *(const short8*)(&exT[h * 16 + lm][ks * 32 + lk]);
    short o = (lm == 0) ? (short)0x3F80 : (short)0;   // bf16 1.0 in column 0
    short8 onesf = {o, o, o, o, o, o, o, o};

    f32x4 pacc[4], dacc;
    { f32x4 z = {0.f,0.f,0.f,0.f}; pacc[0]=z; pacc[1]=z; pacc[2]=z; pacc[3]=z; dacc=z; }
#pragma unroll
    for (int ks = 0; ks < 2; ++ks) {
#pragma unroll
        for (int nt = 0; nt < 4; ++nt) {
            short8 bp = *(const short8*)(&xlT[h * 64 + nt * 16 + lm][ks * 32 + lk]);
            pacc[nt] = __builtin_amdgcn_mfma_f32_16x16x32_bf16(ap[ks], bp, pacc[nt], 0, 0, 0);
        }
        dacc = __builtin_amdgcn_mfma_f32_16x16x32_bf16(ap[ks], onesf, dacc, 0, 0, 0);
    }

    // ---- store per-tile partials: pvh[blk][h][16r][64c] bf16, denp[blk][h][16r] f32 ----
    unsigned short* pvb = ws_pvh + ((size_t)blk * 4 + h) * 1024;
#pragma unroll
    for (int nt = 0; nt < 4; ++nt)
#pragma unroll
        for (int j = 0; j < 4; ++j)
            pvb[((l >> 4) * 4 + j) * 64 + nt * 16 + lm] = f2bf(pacc[nt][j]);
    if (lm == 0) {
#pragma unroll
        for (int j = 0; j < 4; ++j)
            ws_denp[((size_t)blk * 4 + h) * 16 + (l >> 4) * 4 + j] = dacc[j];
    }

    // ---- last block of each graph finalizes (atomic elects; values deterministic) ----
    __syncthreads();                          // implies vmcnt(0): block's stores issued
    if (t == 0) {
        __threadfence();                      // release partials device-wide
        s_flag = (atomicAdd(&cnt[g], 1) == 15);
    }
    __syncthreads();
    if (!s_flag) return;
    __threadfence();                          // acquire other blocks' partials

    int c = t & 63, r0 = t >> 6;
    float vout[4];
#pragma unroll
    for (int j = 0; j < 4; ++j) {
        int r = r0 * 4 + j;
        float s = 0.f;
#pragma unroll
        for (int hh = 0; hh < 4; ++hh) {
            float num = 0.f, den = 0.f;
#pragma unroll
            for (int tl = 0; tl < 16; ++tl) {
                num += bf2f(ws_pvh[(((size_t)(g * 16 + tl)) * 4 + hh) * 1024 + r * 64 + c]);
                den += ws_denp[((size_t)(g * 16 + tl) * 4 + hh) * 16 + r];
            }
            s += num / den;
        }
        vout[j] = fmaf(0.25f, s, bias[c]);
    }
#pragma unroll
    for (int j = 0; j < 4; ++j)
        out[((size_t)g * 16 + r0 * 4 + j) * 64 + c] = vout[j];
}

extern "C" void kernel_launch(void* const* d_in, const int* in_sizes, int n_in,
                              void* d_out, int out_size, void* d_ws, size_t ws_size,
                              hipStream_t stream) {
    const float* x    = (const float*)d_in[0];
    const float* xcb  = (const float*)d_in[3];
    const float* W_l  = (const float*)d_in[4];
    const float* b_l  = (const float*)d_in[5];
    const float* W_r  = (const float*)d_in[6];
    const float* b_r  = (const float*)d_in[7];
    const float* att  = (const float*)d_in[8];
    const float* bias = (const float*)d_in[9];
    float* out = (float*)d_out;

    // workspace layout (~4.3 MB)
    unsigned short* ws_pvh = (unsigned short*)d_ws;       // 512 blk x 4 h x 16 r x 64 c bf16
    float* ws_denp = (float*)(ws_pvh + 2097152);          // 512 x 4 x 16 f32
    float* xrT     = ws_denp + 32768;                     // [hc][16r]
    float* xr_att6 = xrT + 4096;                          // 64
    float* att6    = xr_att6 + 64;                        // 256
    float* att4    = att6 + 256;                          // 256
    unsigned short* wt = (unsigned short*)(att4 + 256);   // 256x64 bf16
    int* cnt = (int*)(wt + 16384);                        // 32 per-graph counters

    k0_prep<<<17, 256, 0, stream>>>(xcb, W_l, W_r, b_r, att, xrT, xr_att6, att6, att4,
                                    wt, cnt, out);
    k1_fused<<<512, 256, 0, stream>>>(x, wt, b_l, att6, att4, xrT, xr_att6, bias,
                                      ws_pvh, ws_denp, cnt, out);
}

// Round 7
// 29.932 us; speedup vs baseline: 2.5813x; 2.3887x over previous
//
#include <hip/hip_runtime.h>

// BipartPool fused: GATv2 bipartite pooling, fully-regular structure.
// lrelu(z) = 0.6z + 0.4|z| -> logit = dot(xl,att6) + xr_att6[r,h] + sum_c |xl+xr|*att4
// No-max softmax (logits ~N(0,1), f32 exp safe): alpha = ex/den, den divided out at the
// end; PV runs on unnormalized ex, den comes free as a ones-column MFMA.
// 3 launches (kernel boundary = the cheap coherence point; fused last-block finalize with
// __threadfence caused 512 L2 wbl2/inv storms on this 8-XCD chip -> 67us, reverted):
//   k0: constant tables + batchcent
//   k1: per 64-node tile: MFMA x@W_l -> xlT(LDS) -> logit pass -> ex(LDS) -> MFMA ex^T@xl
//       (+ones col = den) -> bf16 per-tile partial slots (private, no atomics)
//   k2: reduce 16 tiles, 0.25*sum_h num/den + bias -> out

typedef __attribute__((ext_vector_type(8))) short short8;
typedef __attribute__((ext_vector_type(4))) float f32x4;

#define NPG 1024
#define NT 512

static __device__ __forceinline__ unsigned short f2bf(float f) {
    unsigned int u = __float_as_uint(f);
    u += 0x7fffu + ((u >> 16) & 1u);        // RNE (data is normal, no NaN handling)
    return (unsigned short)(u >> 16);
}
static __device__ __forceinline__ float bf2f(unsigned short u) {
    return __uint_as_float(((unsigned int)u) << 16);
}

// ---------------- K0: tables xrT[hc][16r], xr_att6, att6/att4, Wt bf16; batchcent --------
__global__ __launch_bounds__(256) void k0_prep(const float* __restrict__ xcb,
                                               const float* __restrict__ W_l,
                                               const float* __restrict__ W_r,
                                               const float* __restrict__ b_r,
                                               const float* __restrict__ att,
                                               float* __restrict__ xrT,
                                               float* __restrict__ xr_att6,
                                               float* __restrict__ att6,
                                               float* __restrict__ att4,
                                               unsigned short* __restrict__ wt,
                                               float* __restrict__ out) {
    int b = blockIdx.x, t = threadIdx.x;
    if (b < 16) {
        int r = b, hc = t;                  // one wave per head; W_r coalesced over hc
        float v = b_r[hc];
#pragma unroll
        for (int k = 0; k < 64; ++k)
            v = fmaf(xcb[r * 64 + k], W_r[k * 256 + hc], v);
        xrT[hc * 16 + r] = v;               // [hc][16r]: k1 streams 16-r rows per c
        float p = 0.6f * att[hc] * v;
        p += __shfl_xor(p, 1);  p += __shfl_xor(p, 2);
        p += __shfl_xor(p, 4);  p += __shfl_xor(p, 8);
        p += __shfl_xor(p, 16); p += __shfl_xor(p, 32);
        if ((t & 63) == 0) xr_att6[r * 4 + (t >> 6)] = p;
    } else {
        att6[t] = 0.6f * att[t];
        att4[t] = 0.4f * att[t];
        // Wt[c][k] = bf16(W_l[k][c])  (k-contiguous for MFMA B-frags)
        unsigned short tmp[64] __attribute__((aligned(16)));
#pragma unroll
        for (int k = 0; k < 64; ++k) tmp[k] = f2bf(W_l[k * 256 + t]);
#pragma unroll
        for (int q = 0; q < 8; ++q)
            *(short8*)(wt + t * 64 + q * 8) = *(const short8*)(tmp + q * 8);
        // batchcent: input-independent
        out[NT * 64 + t]       = (float)(t >> 4);
        out[NT * 64 + 256 + t] = (float)((256 + t) >> 4);
    }
}

// ---------------- K1: fused xl -> logits -> ex -> PV bf16 partials -----------------------
__global__ __launch_bounds__(256, 2) void k1_fused(const float* __restrict__ x,
                                                   const unsigned short* __restrict__ wt,
                                                   const float* __restrict__ b_l,
                                                   const float* __restrict__ att6,
                                                   const float* __restrict__ att4,
                                                   const float* __restrict__ xrT,
                                                   const float* __restrict__ xr_att6,
                                                   unsigned short* __restrict__ ws_pvh,
                                                   float* __restrict__ ws_denp) {
    __shared__ __align__(16) unsigned char smraw[(256 + 64) * 72 * 2];
    unsigned short (*As)[72]  = (unsigned short (*)[72])smraw;             // 64x72 (aliases xlT)
    unsigned short (*xlT)[72] = (unsigned short (*)[72])smraw;             // [h*64+c][n]
    unsigned short (*exT)[72] = (unsigned short (*)[72])(smraw + 256 * 72 * 2); // [h*16+r][n]

    const int t = threadIdx.x;
    const int blk = blockIdx.x;              // 512 = g(32) x tile(16)
    const int n0 = blk * 64;

    // ---- phase A: stage x[64n][64k] f32 -> bf16 As ----
    {
        int n = t >> 2, q = (t & 3) * 16;
        const float* p = x + (size_t)(n0 + n) * 64 + q;
        float4 v0 = *(const float4*)p;
        float4 v1 = *(const float4*)(p + 4);
        float4 v2 = *(const float4*)(p + 8);
        float4 v3 = *(const float4*)(p + 12);
        unsigned short h16[16] __attribute__((aligned(16)));
        h16[0]=f2bf(v0.x); h16[1]=f2bf(v0.y); h16[2]=f2bf(v0.z); h16[3]=f2bf(v0.w);
        h16[4]=f2bf(v1.x); h16[5]=f2bf(v1.y); h16[6]=f2bf(v1.z); h16[7]=f2bf(v1.w);
        h16[8]=f2bf(v2.x); h16[9]=f2bf(v2.y); h16[10]=f2bf(v2.z); h16[11]=f2bf(v2.w);
        h16[12]=f2bf(v3.x); h16[13]=f2bf(v3.y); h16[14]=f2bf(v3.z); h16[15]=f2bf(v3.w);
        *(short8*)(&As[n][q])     = *(const short8*)h16;
        *(short8*)(&As[n][q + 8]) = *(const short8*)(h16 + 8);
    }
    __syncthreads();

    const int l = t & 63;
    const int h = __builtin_amdgcn_readfirstlane(t >> 6);
    const int lm = l & 15, lk = (l >> 4) * 8;

    // ---- phase B: MFMA C[64n][64c] = x @ W_l(head h) ----
    short8 af[4][2], bfr[4][2];
#pragma unroll
    for (int mt = 0; mt < 4; ++mt)
#pragma unroll
        for (int ks = 0; ks < 2; ++ks)
            af[mt][ks] = *(const short8*)(&As[mt * 16 + lm][ks * 32 + lk]);
#pragma unroll
    for (int nt = 0; nt < 4; ++nt)
#pragma unroll
        for (int ks = 0; ks < 2; ++ks)
            bfr[nt][ks] = *(const short8*)(wt + (size_t)(h * 64 + nt * 16 + lm) * 64 + ks * 32 + lk);

    f32x4 acc[4][4];
#pragma unroll
    for (int mt = 0; mt < 4; ++mt)
#pragma unroll
        for (int nt = 0; nt < 4; ++nt) { f32x4 z = {0.f,0.f,0.f,0.f}; acc[mt][nt] = z; }
#pragma unroll
    for (int mt = 0; mt < 4; ++mt)
#pragma unroll
        for (int nt = 0; nt < 4; ++nt)
#pragma unroll
            for (int ks = 0; ks < 2; ++ks)
                acc[mt][nt] = __builtin_amdgcn_mfma_f32_16x16x32_bf16(
                    af[mt][ks], bfr[nt][ks], acc[mt][nt], 0, 0, 0);

    __syncthreads();   // all waves done reading As; xlT may overwrite it

    // ---- phase C: acc(+b_l) -> xlT[h*64+c][n] bf16 ----
    // C layout: col = lane&15 (+nt*16), row(n) = (lane>>4)*4 + j (+mt*16)   [m89-verified]
#pragma unroll
    for (int nt = 0; nt < 4; ++nt) {
        float bl = b_l[h * 64 + nt * 16 + lm];
#pragma unroll
        for (int mt = 0; mt < 4; ++mt) {
            unsigned int d0 = (unsigned int)f2bf(acc[mt][nt][0] + bl) |
                              ((unsigned int)f2bf(acc[mt][nt][1] + bl) << 16);
            unsigned int d1 = (unsigned int)f2bf(acc[mt][nt][2] + bl) |
                              ((unsigned int)f2bf(acc[mt][nt][3] + bl) << 16);
            *(uint2*)(&xlT[h * 64 + nt * 16 + lm][mt * 16 + (l >> 4) * 4]) = make_uint2(d0, d1);
        }
    }

    // ---- phase D: stream c; lacc[16]; xr/att wave-uniform loads ----
    float base = 0.f;
    float lacc[16];
#pragma unroll
    for (int r = 0; r < 16; ++r) lacc[r] = 0.f;
#pragma unroll 8
    for (int c = 0; c < 64; ++c) {
        float xv = bf2f(xlT[h * 64 + c][l]);
        base = fmaf(xv, att6[h * 64 + c], base);
        float a4 = att4[h * 64 + c];
        const float* xp = xrT + (size_t)(h * 64 + c) * 16;
#pragma unroll
        for (int r = 0; r < 16; ++r)
            lacc[r] = fmaf(fabsf(xv + xp[r]), a4, lacc[r]);   // abs = free VOP3 modifier
    }
#pragma unroll
    for (int r = 0; r < 16; ++r) {
        float ex = __expf(base + lacc[r] + xr_att6[r * 4 + h]);   // no-max softmax
        exT[h * 16 + r][l] = f2bf(ex);
    }

    // ---- phase E: PV MFMA: pacc[16r][64c] = ex^T @ xl ; ones-col B gives den ----
    short8 ap[2];
#pragma unroll
    for (int ks = 0; ks < 2; ++ks)
        ap[ks] = *(const short8*)(&exT[h * 16 + lm][ks * 32 + lk]);
    short o = (lm == 0) ? (short)0x3F80 : (short)0;   // bf16 1.0 in column 0
    short8 onesf = {o, o, o, o, o, o, o, o};

    f32x4 pacc[4], dacc;
    { f32x4 z = {0.f,0.f,0.f,0.f}; pacc[0]=z; pacc[1]=z; pacc[2]=z; pacc[3]=z; dacc=z; }
#pragma unroll
    for (int ks = 0; ks < 2; ++ks) {
#pragma unroll
        for (int nt = 0; nt < 4; ++nt) {
            short8 bp = *(const short8*)(&xlT[h * 64 + nt * 16 + lm][ks * 32 + lk]);
            pacc[nt] = __builtin_amdgcn_mfma_f32_16x16x32_bf16(ap[ks], bp, pacc[nt], 0, 0, 0);
        }
        dacc = __builtin_amdgcn_mfma_f32_16x16x32_bf16(ap[ks], onesf, dacc, 0, 0, 0);
    }

    // ---- store per-tile partials: pvh[blk][h][16r][64c] bf16, denp[blk][h][16r] f32 ----
    unsigned short* pvb = ws_pvh + ((size_t)blk * 4 + h) * 1024;
#pragma unroll
    for (int nt = 0; nt < 4; ++nt)
#pragma unroll
        for (int j = 0; j < 4; ++j)
            pvb[((l >> 4) * 4 + j) * 64 + nt * 16 + lm] = f2bf(pacc[nt][j]);
    if (lm == 0) {
#pragma unroll
        for (int j = 0; j < 4; ++j)
            ws_denp[((size_t)blk * 4 + h) * 16 + (l >> 4) * 4 + j] = dacc[j];
    }
}

// ---------------- K2: reduce 16 tiles: out = 0.25*sum_h num/den + bias ------------------
__global__ __launch_bounds__(256) void k2_final(const unsigned short* __restrict__ ws_pvh,
                                                const float* __restrict__ ws_denp,
                                                const float* __restrict__ bias,
                                                float* __restrict__ out) {
    int b = blockIdx.x;                         // 128 = g(32) x rquad(4)
    int g = b >> 2;
    int r = (b & 3) * 4 + (threadIdx.x >> 6);   // wave-uniform -> den via s_loads
    int c = threadIdx.x & 63;
    float acc = 0.f;
#pragma unroll
    for (int h = 0; h < 4; ++h) {
        float num = 0.f, den = 0.f;
#pragma unroll
        for (int tl = 0; tl < 16; ++tl) {
            num += bf2f(ws_pvh[(((size_t)(g * 16 + tl)) * 4 + h) * 1024 + r * 64 + c]);
            den += ws_denp[((size_t)(g * 16 + tl) * 4 + h) * 16 + r];
        }
        acc += num / den;
    }
    out[(size_t)(g * 16 + r) * 64 + c] = fmaf(0.25f, acc, bias[c]);
}

extern "C" void kernel_launch(void* const* d_in, const int* in_sizes, int n_in,
                              void* d_out, int out_size, void* d_ws, size_t ws_size,
                              hipStream_t stream) {
    const float* x    = (const float*)d_in[0];
    const float* xcb  = (const float*)d_in[3];
    const float* W_l  = (const float*)d_in[4];
    const float* b_l  = (const float*)d_in[5];
    const float* W_r  = (const float*)d_in[6];
    const float* b_r  = (const float*)d_in[7];
    const float* att  = (const float*)d_in[8];
    const float* bias = (const float*)d_in[9];
    float* out = (float*)d_out;

    // workspace layout (~4.3 MB)
    unsigned short* ws_pvh = (unsigned short*)d_ws;       // 512 blk x 4 h x 16 r x 64 c bf16
    float* ws_denp = (float*)(ws_pvh + 2097152);          // 512 x 4 x 16 f32
    float* xrT     = ws_denp + 32768;                     // [hc][16r]
    float* xr_att6 = xrT + 4096;                          // 64
    float* att6    = xr_att6 + 64;                        // 256
    float* att4    = att6 + 256;                          // 256
    unsigned short* wt = (unsigned short*)(att4 + 256);   // 256x64 bf16

    k0_prep<<<17, 256, 0, stream>>>(xcb, W_l, W_r, b_r, att, xrT, xr_att6, att6, att4, wt, out);
    k1_fused<<<512, 256, 0, stream>>>(x, wt, b_l, att6, att4, xrT, xr_att6, ws_pvh, ws_denp);
    k2_final<<<128, 256, 0, stream>>>(ws_pvh, ws_denp, bias, out);
}